// Round 7
// baseline (31.925 us; speedup 1.0000x reference)
//
#include <hip/hip_runtime.h>

// YOLOv3 loss on MI355X — round 7.
// R6 post-mortem: the ch-4 GATHER (170K scattered 64B lines) was the ~20us
// floor; the R2-style coalesced float4 STREAM of all 58MB ran in ~5us.
// Graph = main kernel + final kernel (2 nodes, no memset, no global atomics).
//   blocks [0,600):    correct — one wave per (scale,b,t); in-register build;
//                      ballots/shuffles; coalesced 85-ch gather at target cells.
//   blocks [600,2648): noobj — grid-stride float4 stream over the 3 tensors,
//                      extract channel-4 values, BCE(0) sum.
// Partials: scorr[27][600] + snoobj[3][2048] (every slot written -> no init).
// final_kernel: 1024 threads, coalesced slot reduction + loss formula.

#define NB 16        // batch
#define NT 50        // targets per batch
#define NA 3         // anchors
#define NC 80        // classes
#define NCORR 600    // correct blocks (600*4 waves = 2400 = 3*16*50)
#define NSTREAM 2048 // stream blocks
#define NBLK 2648

__device__ __forceinline__ float bce0(float p) { return -log1pf(-p); } // target 0
__device__ __forceinline__ float bce1(float p) { return -logf(p); }    // target 1

// scorr row layout j: scale*9 + {0..3 mse, 4 obj, 5 noobj_corr, 6 cls, 7 n_pos, 8 n_zeroed}
__global__ __launch_bounds__(256) void main_kernel(
    const float* __restrict__ o13,
    const float* __restrict__ o26,
    const float* __restrict__ o52,
    const float* __restrict__ targets,
    const float* __restrict__ a13,
    const float* __restrict__ a26,
    const float* __restrict__ a52,
    float* __restrict__ snoobj,     // [3][NSTREAM]
    float* __restrict__ scorr)      // [27][NCORR]
{
    int lane = threadIdx.x & 63;
    int wvid = threadIdx.x >> 6;

    if (blockIdx.x >= NCORR) {
        // ---------------- noobj region: float4 stream, extract ch4 ----------------
        const int STRIDE = NSTREAM * 256;
        int tid = (blockIdx.x - NCORR) * 256 + threadIdx.x;
        float s0 = 0.0f, s1 = 0.0f, s2 = 0.0f;
        const float4* p13 = (const float4*)o13;
        const float4* p26 = (const float4*)o26;
        const float4* p52 = (const float4*)o52;
        for (int i = tid; i < 172380; i += STRIDE) {        // 8112*85/4
            float4 v = p13[i];
            int k = 4 - (int)(((unsigned)i * 4u) % 85u);
            if (k >= 0 && k <= 3)
                s0 += bce0(k == 0 ? v.x : k == 1 ? v.y : k == 2 ? v.z : v.w);
        }
        for (int i = tid; i < 689520; i += STRIDE) {        // 32448*85/4
            float4 v = p26[i];
            int k = 4 - (int)(((unsigned)i * 4u) % 85u);
            if (k >= 0 && k <= 3)
                s1 += bce0(k == 0 ? v.x : k == 1 ? v.y : k == 2 ? v.z : v.w);
        }
        for (int i = tid; i < 2758080; i += STRIDE) {       // 129792*85/4
            float4 v = p52[i];
            int k = 4 - (int)(((unsigned)i * 4u) % 85u);
            if (k >= 0 && k <= 3)
                s2 += bce0(k == 0 ? v.x : k == 1 ? v.y : k == 2 ? v.z : v.w);
        }
        __shared__ float red[4][3];
        float v3[3] = { s0, s1, s2 };
        #pragma unroll
        for (int j = 0; j < 3; ++j) {
            float x = v3[j];
            #pragma unroll
            for (int off = 32; off; off >>= 1) x += __shfl_down(x, off);
            if (lane == 0) red[wvid][j] = x;
        }
        __syncthreads();
        if (threadIdx.x < 3)
            snoobj[threadIdx.x * NSTREAM + (blockIdx.x - NCORR)] =
                red[0][threadIdx.x] + red[1][threadIdx.x]
              + red[2][threadIdx.x] + red[3][threadIdx.x];
        return;
    }

    // ---------------- correct region ----------------
    __shared__ float sacc[27];
    if (threadIdx.x < 27) sacc[threadIdx.x] = 0.0f;
    __syncthreads();

    int wid = blockIdx.x * 4 + wvid;                // 0..2399
    int scale = wid / (NB * NT);
    int rem   = wid - scale * (NB * NT);
    int b = rem / NT, t = rem - b * NT;

    int G = (scale == 0) ? 13 : (scale == 1) ? 26 : 52;
    const float* out  = (scale == 0) ? o13 : (scale == 1) ? o26 : o52;
    const float* anch = (scale == 0) ? a13 : (scale == 1) ? a26 : a52;

    // in-register build: lane l computes target l's record
    unsigned mt = 0xFFFFFFFFu;
    float tx = 0.0f, ty = 0.0f, tw = 0.0f, th = 0.0f;
    {
        int li = (lane < NT) ? lane : NT - 1;       // clamped addr, masked below
        const float* tg = targets + ((size_t)b * NT + li) * 5;
        float x1 = tg[0], y1 = tg[1], x2 = tg[2], y2 = tg[3];
        int cls = (int)tg[4];
        float gf = (float)G;
        float bx = 0.5f * (x1 + x2) * gf;
        float by = 0.5f * (y1 + y2) * gf;
        float bw = (x2 - x1) * gf;
        float bh = (y2 - y1) * gf;
        int best = 0; float bestiou = -1.0f, aw_b = 1.0f, ah_b = 1.0f;
        unsigned nmz = 0;
        #pragma unroll
        for (int a = 0; a < NA; ++a) {
            float aw = anch[2 * a], ah = anch[2 * a + 1];
            float inter = fminf(aw, bw) * fminf(ah, bh);
            float uni = 1e-8f + aw * ah + bw * bh - inter;
            float iou = inter / uni;
            if (iou > 0.5f) nmz |= (1u << a);
            if (iou > bestiou) { bestiou = iou; best = a; aw_b = aw; ah_b = ah; }
        }
        int gi = (int)bx; gi = gi < 0 ? 0 : (gi > G - 1 ? G - 1 : gi);
        int gj = (int)by; gj = gj < 0 ? 0 : (gj > G - 1 ? G - 1 : gj);
        tx = bx - floorf(bx);
        ty = by - floorf(by);
        tw = logf(bw / aw_b);
        th = logf(bh / ah_b);
        if (lane < NT)
            mt = (unsigned)gi | ((unsigned)gj << 6) | ((unsigned)best << 12)
               | ((unsigned)cls << 14) | (nmz << 21);
    }

    unsigned key_lane = mt & 0xFFFu;
    unsigned key_t = __shfl(key_lane, t);
    unsigned long long match = __ballot(lane < NT && key_lane == key_t);
    bool canon = ((match & ((1ull << t) - 1ull)) == 0ull);   // wave-uniform

    if (canon) {
        int gi = key_t & 63, gj = (key_t >> 6) & 63;
        #pragma unroll
        for (int a = 0; a < NA; ++a) {
            unsigned long long bestmask =
                __ballot(lane < NT && key_lane == key_t && (int)((mt >> 12) & 3u) == a);
            unsigned long long nmzmask =
                __ballot(lane < NT && key_lane == key_t && ((mt >> (21 + a)) & 1u));
            bool pos = bestmask != 0ull;
            bool zeroed = pos || (nmzmask != 0ull);
            if (!zeroed) continue;                  // wave-uniform

            const float* pc = out + (((size_t)(b * NA + a) * G + gj) * G + gi) * 85;
            float vlo = pc[lane];                   // channels 0..63, coalesced
            if (lane == 4) {                        // noobj correction
                atomicAdd(&sacc[scale * 9 + 5], -bce0(vlo));
                atomicAdd(&sacc[scale * 9 + 8], 1.0f);
            }
            if (pos) {
                float vhi = (lane < 21) ? pc[64 + lane] : 0.0f;  // ch 64..84
                int lastt = 63 - __clzll(bestmask);  // last-write-wins
                float ltx = __shfl(tx, lastt), lty = __shfl(ty, lastt);
                float ltw = __shfl(tw, lastt), lth = __shfl(th, lastt);
                // class-bit union across matching-best lanes
                unsigned c0 = 0, c1 = 0, c2 = 0;
                if ((bestmask >> lane) & 1ull) {
                    int c = (mt >> 14) & 127;
                    if (c < 32) c0 = 1u << c;
                    else if (c < 64) c1 = 1u << (c - 32);
                    else c2 = 1u << (c - 64);
                }
                #pragma unroll
                for (int off = 32; off; off >>= 1) {
                    c0 |= __shfl_xor(c0, off);
                    c1 |= __shfl_xor(c1, off);
                    c2 |= __shfl_xor(c2, off);
                }
                // lane-parallel class BCE: lane -> channel lane and 64+lane
                float cls = 0.0f;
                if (lane >= 5) {
                    int c = lane - 5;               // 0..58
                    unsigned w = (c < 32) ? c0 : c1;
                    cls += ((w >> (c & 31)) & 1u) ? bce1(vlo) : bce0(vlo);
                }
                if (lane < 21) {
                    int c = lane + 59;              // 59..79
                    unsigned w = (c < 64) ? c1 : c2;
                    cls += ((w >> (c & 31)) & 1u) ? bce1(vhi) : bce0(vhi);
                }
                #pragma unroll
                for (int off = 32; off; off >>= 1) cls += __shfl_xor(cls, off);
                if (lane == 0) {
                    atomicAdd(&sacc[scale * 9 + 6], cls);
                    atomicAdd(&sacc[scale * 9 + 7], 1.0f);
                }
                if (lane < 4) {                     // mse terms
                    float tv = (lane == 0) ? ltx : (lane == 1) ? lty
                             : (lane == 2) ? ltw : lth;
                    float d = vlo - tv;
                    atomicAdd(&sacc[scale * 9 + lane], d * d);
                }
                if (lane == 4) atomicAdd(&sacc[scale * 9 + 4], bce1(vlo));
            }
        }
    }
    __syncthreads();
    if (threadIdx.x < 27)
        scorr[threadIdx.x * NCORR + blockIdx.x] = sacc[threadIdx.x];
}

// ---------------- final: reduce slots + combine scales ----------------
__global__ __launch_bounds__(1024) void final_kernel(
    const float* __restrict__ snoobj,   // [3][NSTREAM]
    const float* __restrict__ scorr,    // [27][NCORR]
    float* __restrict__ outp)
{
    float s[30];
    #pragma unroll
    for (int j = 0; j < 30; ++j) s[j] = 0.0f;
    for (int c = threadIdx.x; c < NSTREAM; c += 1024) {
        #pragma unroll
        for (int j = 0; j < 3; ++j) s[27 + j] += snoobj[j * NSTREAM + c];
    }
    if (threadIdx.x < NCORR) {
        #pragma unroll
        for (int j = 0; j < 27; ++j) s[j] += scorr[j * NCORR + threadIdx.x];
    }
    __shared__ float red[16][30];
    int lane = threadIdx.x & 63, wv = threadIdx.x >> 6;
    #pragma unroll
    for (int j = 0; j < 30; ++j) {
        float x = s[j];
        #pragma unroll
        for (int off = 32; off; off >>= 1) x += __shfl_down(x, off);
        if (lane == 0) red[wv][j] = x;
    }
    __syncthreads();
    if (threadIdx.x < 30) {
        float x = 0.0f;
        #pragma unroll
        for (int w = 0; w < 16; ++w) x += red[w][threadIdx.x];
        red[0][threadIdx.x] = x;
    }
    __syncthreads();
    if (threadIdx.x == 0) {
        const float Stot[3] = { 8112.0f, 32448.0f, 129792.0f };
        float total = 0.0f;
        #pragma unroll
        for (int sc = 0; sc < 3; ++sc) {
            float np = red[0][sc * 9 + 7];
            float nn = Stot[sc] - red[0][sc * 9 + 8];
            float noobj = red[0][27 + sc] + red[0][sc * 9 + 5];
            total += (red[0][sc*9+0] + red[0][sc*9+1] + red[0][sc*9+2]
                    + red[0][sc*9+3] + red[0][sc*9+4]) / np
                   + noobj / nn * 100.0f
                   + red[0][sc*9+6] / (np * (float)NC);
        }
        outp[0] = total;
    }
}

extern "C" void kernel_launch(void* const* d_in, const int* in_sizes, int n_in,
                              void* d_out, int out_size, void* d_ws, size_t ws_size,
                              hipStream_t stream)
{
    const float* out13   = (const float*)d_in[0];
    const float* out26   = (const float*)d_in[1];
    const float* out52   = (const float*)d_in[2];
    const float* targets = (const float*)d_in[3];
    const float* a13     = (const float*)d_in[4];
    const float* a26     = (const float*)d_in[5];
    const float* a52     = (const float*)d_in[6];

    // ws: snoobj[3][2048] at 0 (24576 B); scorr[27][600] at 24576 (64800 B)
    float* snoobj = (float*)d_ws;
    float* scorr  = (float*)((char*)d_ws + 24576);

    main_kernel<<<NBLK, 256, 0, stream>>>(
        out13, out26, out52, targets, a13, a26, a52, snoobj, scorr);

    final_kernel<<<1, 1024, 0, stream>>>(snoobj, scorr, (float*)d_out);
}

// Round 8
// 21.058 us; speedup vs baseline: 1.5161x; 1.5161x over previous
//
#include <hip/hip_runtime.h>

// YOLOv3 loss on MI355X — round 8.
// Model (fits R2..R7): the wave-correct region's SERIAL latency chain
// (~7 cold-memory round trips + 54 shuffles per wave) was the ~22us pole.
// Fix: prefetch ALL 6 cell vectors (3 anchors x lo/hi) right after key_t is
// known; compute all ballots while loads fly; single-writer fast path for the
// class union (1 shfl instead of 18 per anchor).
// Graph = main kernel + final kernel.
//   blocks [0,600):    correct — one wave per (scale,b,t)
//   blocks [600,1266): noobj — gather ch4 of every cell (1/thread)

#define NB 16      // batch
#define NT 50      // targets per batch
#define NA 3       // anchors
#define NC 80      // classes
#define NCORR 600  // correct blocks (600*4 waves = 2400 = 3*16*50)
#define NNOOBJ 666 // noobj blocks: 32 (s0) + 127 (s1) + 507 (s2)
#define NBLK 1266

__device__ __forceinline__ float bce0(float p) { return -log1pf(-p); } // target 0
__device__ __forceinline__ float bce1(float p) { return -logf(p); }    // target 1

// scorr row j: scale*9 + {0..3 mse, 4 obj, 5 noobj_corr, 6 cls, 7 n_pos, 8 n_zeroed}
__global__ __launch_bounds__(256) void main_kernel(
    const float* __restrict__ o13,
    const float* __restrict__ o26,
    const float* __restrict__ o52,
    const float* __restrict__ targets,
    const float* __restrict__ a13,
    const float* __restrict__ a26,
    const float* __restrict__ a52,
    float* __restrict__ snoobj,     // [3][NNOOBJ]
    float* __restrict__ scorr)      // [27][NCORR]
{
    int lane = threadIdx.x & 63;
    int wvid = threadIdx.x >> 6;

    if (blockIdx.x >= NCORR) {
        // ---------------- noobj region: gather ch4 of every cell ----------------
        __shared__ float red4[4];
        int nb = blockIdx.x - NCORR;
        const float* p; int li, cnt, scale;
        if (nb < 32)       { p = o13; scale = 0; li = nb * 256 + threadIdx.x;         cnt = 8112;   }
        else if (nb < 159) { p = o26; scale = 1; li = (nb - 32) * 256 + threadIdx.x;  cnt = 32448;  }
        else               { p = o52; scale = 2; li = (nb - 159) * 256 + threadIdx.x; cnt = 129792; }
        float bv = (li < cnt) ? bce0(p[(size_t)li * 85 + 4]) : 0.0f;
        #pragma unroll
        for (int off = 32; off; off >>= 1) bv += __shfl_down(bv, off);
        if (lane == 0) red4[wvid] = bv;
        __syncthreads();
        if (threadIdx.x < 3) {
            float x = ((int)threadIdx.x == scale)
                    ? (red4[0] + red4[1] + red4[2] + red4[3]) : 0.0f;
            snoobj[threadIdx.x * NNOOBJ + nb] = x;
        }
        return;
    }

    // ---------------- correct region ----------------
    __shared__ float sacc[27];
    if (threadIdx.x < 27) sacc[threadIdx.x] = 0.0f;
    __syncthreads();

    int wid = blockIdx.x * 4 + wvid;                // 0..2399
    int scale = wid / (NB * NT);
    int rem   = wid - scale * (NB * NT);
    int b = rem / NT, t = rem - b * NT;

    int G = (scale == 0) ? 13 : (scale == 1) ? 26 : 52;
    const float* out  = (scale == 0) ? o13 : (scale == 1) ? o26 : o52;
    const float* anch = (scale == 0) ? a13 : (scale == 1) ? a26 : a52;

    // in-register build: lane l computes target l's record
    unsigned mt = 0xFFFFFFFFu;
    float tx = 0.0f, ty = 0.0f, tw = 0.0f, th = 0.0f;
    {
        int li = (lane < NT) ? lane : NT - 1;       // clamped addr, masked below
        const float* tg = targets + ((size_t)b * NT + li) * 5;
        float x1 = tg[0], y1 = tg[1], x2 = tg[2], y2 = tg[3];
        int cls = (int)tg[4];
        float gf = (float)G;
        float bx = 0.5f * (x1 + x2) * gf;
        float by = 0.5f * (y1 + y2) * gf;
        float bw = (x2 - x1) * gf;
        float bh = (y2 - y1) * gf;
        int best = 0; float bestiou = -1.0f, aw_b = 1.0f, ah_b = 1.0f;
        unsigned nmz = 0;
        #pragma unroll
        for (int a = 0; a < NA; ++a) {
            float aw = anch[2 * a], ah = anch[2 * a + 1];
            float inter = fminf(aw, bw) * fminf(ah, bh);
            float uni = 1e-8f + aw * ah + bw * bh - inter;
            float iou = inter / uni;
            if (iou > 0.5f) nmz |= (1u << a);
            if (iou > bestiou) { bestiou = iou; best = a; aw_b = aw; ah_b = ah; }
        }
        int gi = (int)bx; gi = gi < 0 ? 0 : (gi > G - 1 ? G - 1 : gi);
        int gj = (int)by; gj = gj < 0 ? 0 : (gj > G - 1 ? G - 1 : gj);
        tx = bx - floorf(bx);
        ty = by - floorf(by);
        tw = logf(bw / aw_b);
        th = logf(bh / ah_b);
        if (lane < NT)
            mt = (unsigned)gi | ((unsigned)gj << 6) | ((unsigned)best << 12)
               | ((unsigned)cls << 14) | (nmz << 21);
    }

    unsigned key_lane = mt & 0xFFFu;
    unsigned key_t = __shfl(key_lane, t);
    unsigned long long match = __ballot(lane < NT && key_lane == key_t);
    bool canon = ((match & ((1ull << t) - 1ull)) == 0ull);   // wave-uniform

    if (canon) {
        int gi = key_t & 63, gj = (key_t >> 6) & 63;

        // ---- ISSUE ALL CELL LOADS UP FRONT (3 anchors x lo/hi) ----
        const float* pc0 = out + (((size_t)(b * NA + 0) * G + gj) * G + gi) * 85;
        const float* pc1 = out + (((size_t)(b * NA + 1) * G + gj) * G + gi) * 85;
        const float* pc2 = out + (((size_t)(b * NA + 2) * G + gj) * G + gi) * 85;
        float vlo0 = pc0[lane], vlo1 = pc1[lane], vlo2 = pc2[lane];
        int hl = (lane < 21) ? 64 + lane : lane;    // valid addr; hi lanes unused
        float vhi0 = pc0[hl], vhi1 = pc1[hl], vhi2 = pc2[hl];

        // ---- all ballots while loads fly ----
        bool mk = (lane < NT) && (key_lane == key_t);
        int bsel = (mt >> 12) & 3;
        unsigned long long bm0 = __ballot(mk && bsel == 0);
        unsigned long long bm1 = __ballot(mk && bsel == 1);
        unsigned long long bm2 = __ballot(mk && bsel == 2);
        unsigned long long nz0 = __ballot(mk && ((mt >> 21) & 1u));
        unsigned long long nz1 = __ballot(mk && ((mt >> 22) & 1u));
        unsigned long long nz2 = __ballot(mk && ((mt >> 23) & 1u));
        int myc = (mt >> 14) & 127;

        #define ANCHOR_BLOCK(A, BM, NZ, VLO, VHI)                                   \
        {                                                                           \
            bool pos = (BM) != 0ull;                                                \
            if (pos || (NZ) != 0ull) {                                              \
                if (lane == 4) {                    /* noobj correction */          \
                    atomicAdd(&sacc[scale * 9 + 5], -bce0(VLO));                    \
                    atomicAdd(&sacc[scale * 9 + 8], 1.0f);                          \
                }                                                                   \
                if (pos) {                                                          \
                    int lastt = 63 - __clzll(BM);   /* last-write-wins */           \
                    float ltx = __shfl(tx, lastt), lty = __shfl(ty, lastt);         \
                    float ltw = __shfl(tw, lastt), lth = __shfl(th, lastt);         \
                    unsigned c0, c1, c2;                                            \
                    if (__popcll(BM) == 1) {        /* single writer: 1 shfl */     \
                        int lc = __shfl(myc, lastt);                                \
                        c0 = (lc < 32) ? (1u << lc) : 0u;                           \
                        c1 = (lc >= 32 && lc < 64) ? (1u << (lc - 32)) : 0u;        \
                        c2 = (lc >= 64) ? (1u << (lc - 64)) : 0u;                   \
                    } else {                        /* rare: OR butterfly */        \
                        c0 = c1 = c2 = 0u;                                          \
                        if (((BM) >> lane) & 1ull) {                                \
                            if (myc < 32) c0 = 1u << myc;                           \
                            else if (myc < 64) c1 = 1u << (myc - 32);               \
                            else c2 = 1u << (myc - 64);                             \
                        }                                                           \
                        _Pragma("unroll")                                           \
                        for (int off = 32; off; off >>= 1) {                        \
                            c0 |= __shfl_xor(c0, off);                              \
                            c1 |= __shfl_xor(c1, off);                              \
                            c2 |= __shfl_xor(c2, off);                              \
                        }                                                           \
                    }                                                               \
                    float cls = 0.0f;                                               \
                    if (lane >= 5) {                /* channels 0..58 */            \
                        int c = lane - 5;                                           \
                        unsigned w = (c < 32) ? c0 : c1;                            \
                        cls += ((w >> (c & 31)) & 1u) ? bce1(VLO) : bce0(VLO);      \
                    }                                                               \
                    if (lane < 21) {                /* channels 59..79 */           \
                        int c = lane + 59;                                          \
                        unsigned w = (c < 64) ? c1 : c2;                            \
                        cls += ((w >> (c & 31)) & 1u) ? bce1(VHI) : bce0(VHI);      \
                    }                                                               \
                    _Pragma("unroll")                                               \
                    for (int off = 32; off; off >>= 1) cls += __shfl_xor(cls, off); \
                    if (lane == 0) {                                                \
                        atomicAdd(&sacc[scale * 9 + 6], cls);                       \
                        atomicAdd(&sacc[scale * 9 + 7], 1.0f);                      \
                    }                                                               \
                    if (lane < 4) {                 /* mse terms */                 \
                        float tv = (lane == 0) ? ltx : (lane == 1) ? lty            \
                                 : (lane == 2) ? ltw : lth;                         \
                        float d = VLO - tv;                                         \
                        atomicAdd(&sacc[scale * 9 + lane], d * d);                  \
                    }                                                               \
                    if (lane == 4) atomicAdd(&sacc[scale * 9 + 4], bce1(VLO));      \
                }                                                                   \
            }                                                                       \
        }

        ANCHOR_BLOCK(0, bm0, nz0, vlo0, vhi0)
        ANCHOR_BLOCK(1, bm1, nz1, vlo1, vhi1)
        ANCHOR_BLOCK(2, bm2, nz2, vlo2, vhi2)
        #undef ANCHOR_BLOCK
    }
    __syncthreads();
    if (threadIdx.x < 27)
        scorr[threadIdx.x * NCORR + blockIdx.x] = sacc[threadIdx.x];
}

// ---------------- final: reduce slots + combine scales ----------------
__global__ __launch_bounds__(256) void final_kernel(
    const float* __restrict__ snoobj,   // [3][NNOOBJ]
    const float* __restrict__ scorr,    // [27][NCORR]
    float* __restrict__ outp)
{
    float s[30];
    #pragma unroll
    for (int j = 0; j < 30; ++j) s[j] = 0.0f;
    for (int c = threadIdx.x; c < NNOOBJ; c += 256) {
        #pragma unroll
        for (int j = 0; j < 3; ++j) s[27 + j] += snoobj[j * NNOOBJ + c];
    }
    for (int c = threadIdx.x; c < NCORR; c += 256) {
        #pragma unroll
        for (int j = 0; j < 27; ++j) s[j] += scorr[j * NCORR + c];
    }
    __shared__ float red[4][30];
    int lane = threadIdx.x & 63, wv = threadIdx.x >> 6;
    #pragma unroll
    for (int j = 0; j < 30; ++j) {
        float x = s[j];
        #pragma unroll
        for (int off = 32; off; off >>= 1) x += __shfl_down(x, off);
        if (lane == 0) red[wv][j] = x;
    }
    __syncthreads();
    if (threadIdx.x == 0) {
        float a[30];
        #pragma unroll
        for (int j = 0; j < 30; ++j)
            a[j] = red[0][j] + red[1][j] + red[2][j] + red[3][j];
        const float Stot[3] = { 8112.0f, 32448.0f, 129792.0f };
        float total = 0.0f;
        #pragma unroll
        for (int sc = 0; sc < 3; ++sc) {
            float np = a[sc * 9 + 7];
            float nn = Stot[sc] - a[sc * 9 + 8];
            float noobj = a[27 + sc] + a[sc * 9 + 5];
            total += (a[sc*9+0] + a[sc*9+1] + a[sc*9+2] + a[sc*9+3] + a[sc*9+4]) / np
                   + noobj / nn * 100.0f
                   + a[sc*9+6] / (np * (float)NC);
        }
        outp[0] = total;
    }
}

extern "C" void kernel_launch(void* const* d_in, const int* in_sizes, int n_in,
                              void* d_out, int out_size, void* d_ws, size_t ws_size,
                              hipStream_t stream)
{
    const float* out13   = (const float*)d_in[0];
    const float* out26   = (const float*)d_in[1];
    const float* out52   = (const float*)d_in[2];
    const float* targets = (const float*)d_in[3];
    const float* a13     = (const float*)d_in[4];
    const float* a26     = (const float*)d_in[5];
    const float* a52     = (const float*)d_in[6];

    // ws: snoobj[3][666] at 0 (7992 B, pad to 8192); scorr[27][600] at 8192
    float* snoobj = (float*)d_ws;
    float* scorr  = (float*)((char*)d_ws + 8192);

    main_kernel<<<NBLK, 256, 0, stream>>>(
        out13, out26, out52, targets, a13, a26, a52, snoobj, scorr);

    final_kernel<<<1, 256, 0, stream>>>(snoobj, scorr, (float*)d_out);
}